// Round 5
// baseline (93.405 us; speedup 1.0000x reference)
//
#include <hip/hip_runtime.h>

// Segment sum: out[s, f] = sum over rows r with seg[r]==s of memory[r, f].
// memory: [NELEMS, 128] f32, seg: [NELEMS] int32 SORTED ascending,
// out: [NSEG, 128] f32.
//
// Load-balanced variant: each segment is split into SPLIT=4 quarters ->
// 4096 blocks x 256 thr (4 waves). 8 blocks/CU resident (32 waves/CU), the
// rest backfill dynamically as blocks retire -> quarter-segment-granular
// load balancing. Quarters combine via atomicAdd into a memset-zeroed out
// (0.5 MB, L2-resident -> cheap). Per block: wave-parallel 32-ary
// lower_bound finds the segment bounds; branch-free unroll-4 nontemporal
// f32x4 streaming; LDS reduce across 8 row-lanes; 128 float atomics.

#define FEAT 128
#define F4 (FEAT / 4)             // 32 float4 per row
#define ROWLANES 8                // row-lanes per block
#define THREADS (F4 * ROWLANES)   // 256
#define SPLIT 4                   // quarters per segment

typedef float f32x4 __attribute__((ext_vector_type(4)));

__global__ __launch_bounds__(THREADS, 8) void segsum_split(
        const f32x4* __restrict__ mem,    // [nelems, F4]
        const int* __restrict__ seg,      // [nelems], sorted ascending
        float* __restrict__ out,          // [nseg, FEAT], pre-zeroed
        int nelems) {
    const int bid  = blockIdx.x;
    const int s    = bid >> 2;                // segment
    const int q    = bid & (SPLIT - 1);       // quarter
    const int lane = threadIdx.x & (F4 - 1);  // float4 column 0..31
    const int rl   = threadIdx.x >> 5;        // row-lane 0..7

    __shared__ int sb[2];                     // {start, end}

    if (threadIdx.x < 64) {                   // wave 0 only
        const int half = threadIdx.x >> 5;    // 0: lower_bound(s), 1: lower_bound(s+1)
        const int j    = threadIdx.x & 31;
        const int t    = s + half;

        int lo = 0, len = nelems;
        #pragma unroll
        for (int round = 0; round < 4; ++round) {
            int pos = lo + (int)(((long long)j * len) >> 5);
            int v = seg[pos];
            unsigned long long m = __ballot(v < t);
            unsigned mh = half ? (unsigned)(m >> 32) : (unsigned)(m & 0xffffffffull);
            int c = __popc(mh);
            int pcm1 = lo + (int)(((long long)(c - 1) * len) >> 5);
            int pc   = (c < 32) ? (lo + (int)(((long long)c * len) >> 5)) : (lo + len);
            int newlo = (c > 0) ? pcm1 : lo;
            int newhi = (c > 0) ? pc : lo;
            lo = newlo;
            len = newhi - newlo;
        }
        int v = (j < len) ? seg[lo + j] : 0x7fffffff;
        unsigned long long m = __ballot(v < t);
        unsigned mh = half ? (unsigned)(m >> 32) : (unsigned)(m & 0xffffffffull);
        if (j == 0) sb[half] = lo + __popc(mh);
    }
    __syncthreads();

    const int start = sb[0];
    const int len   = sb[1] - start;
    const int r0    = start + (int)(((long long)q * len) / SPLIT);
    const int r1    = start + (int)(((long long)(q + 1) * len) / SPLIT);

    f32x4 a0 = (f32x4)0.f, a1 = (f32x4)0.f, a2 = (f32x4)0.f, a3 = (f32x4)0.f;

    int r = r0 + rl;
    for (; r + 3 * ROWLANES < r1; r += 4 * ROWLANES) {
        f32x4 v0 = __builtin_nontemporal_load(&mem[(size_t)r * F4 + lane]);
        f32x4 v1 = __builtin_nontemporal_load(&mem[(size_t)(r + ROWLANES) * F4 + lane]);
        f32x4 v2 = __builtin_nontemporal_load(&mem[(size_t)(r + 2 * ROWLANES) * F4 + lane]);
        f32x4 v3 = __builtin_nontemporal_load(&mem[(size_t)(r + 3 * ROWLANES) * F4 + lane]);
        a0 += v0; a1 += v1; a2 += v2; a3 += v3;
    }
    for (; r < r1; r += ROWLANES) {
        a0 += __builtin_nontemporal_load(&mem[(size_t)r * F4 + lane]);
    }
    a0 += a1; a2 += a3; a0 += a2;

    // Reduce across the 8 row-lanes via LDS.
    __shared__ f32x4 red[ROWLANES][F4];
    red[rl][lane] = a0;
    __syncthreads();
    if (rl < 2) {
        red[rl][lane] = red[rl][lane] + red[rl + 2][lane] +
                        red[rl + 4][lane] + red[rl + 6][lane];
    }
    __syncthreads();
    if (rl == 0) {
        f32x4 v = red[0][lane] + red[1][lane];
        float* o = out + (size_t)s * FEAT + lane * 4;
        atomicAdd(o + 0, v.x);
        atomicAdd(o + 1, v.y);
        atomicAdd(o + 2, v.z);
        atomicAdd(o + 3, v.w);
    }
}

extern "C" void kernel_launch(void* const* d_in, const int* in_sizes, int n_in,
                              void* d_out, int out_size, void* d_ws, size_t ws_size,
                              hipStream_t stream) {
    const f32x4* mem = (const f32x4*)d_in[0];
    const int* seg = (const int*)d_in[1];
    float* out = (float*)d_out;

    const int nelems = in_sizes[1];     // 1,000,000
    const int nseg = out_size / FEAT;   // 1024

    hipMemsetAsync(out, 0, (size_t)out_size * sizeof(float), stream);

    segsum_split<<<nseg * SPLIT, THREADS, 0, stream>>>(mem, seg, out, nelems);
}

// Round 6
// 81.755 us; speedup vs baseline: 1.1425x; 1.1425x over previous
//
#include <hip/hip_runtime.h>

// Segment sum: out[s, f] = sum over rows r with seg[r]==s of memory[r, f].
// memory: [NELEMS, 128] f32, seg: [NELEMS] int32 SORTED ascending,
// out: [NSEG, 128] f32.
//
// Single fused kernel, one block per segment (512 thr = 8 waves; 1024 blocks
// x 8 waves = 32 waves/CU, whole grid co-resident):
//   prologue: wave 0 finds [start,end) via 32-ary lower_bound on seg
//             (two 32-lane halves search b and b+1; 4 probe rounds + final),
//             result broadcast through LDS.
//   body:     branch-free unroll-4 nontemporal float4 streaming, LDS reduce
//             across 16 row-lanes, one coalesced float4 store per segment.
//   No atomics, no zeroing pass (every out row is written, incl. empty segs).
//
// Round-5 post-mortem: splitting segments 4-way (+memset+atomics) REGRESSED
// 81.4 -> 93.4 us: 4x prologues, 4x block launch overhead, extra dispatch.
// This structure is the measured optimum: 6.30 TB/s effective = m13's
// achievable read-stream BW.

#define FEAT 128
#define F4 (FEAT / 4)             // 32 float4 per row
#define ROWLANES 16               // row-lanes per block
#define THREADS (F4 * ROWLANES)   // 512

typedef float f32x4 __attribute__((ext_vector_type(4)));

__global__ __launch_bounds__(THREADS, 8) void segsum_fused(
        const f32x4* __restrict__ mem,    // [nelems, F4]
        const int* __restrict__ seg,      // [nelems], sorted ascending
        f32x4* __restrict__ out,          // [nseg, F4]
        int nelems) {
    const int b    = blockIdx.x;
    const int lane = threadIdx.x & (F4 - 1);  // float4 column 0..31
    const int rl   = threadIdx.x >> 5;        // row-lane 0..15

    __shared__ int sb[2];                     // {start, end}

    if (threadIdx.x < 64) {                   // wave 0 only
        const int half = threadIdx.x >> 5;    // 0: lower_bound(b), 1: lower_bound(b+1)
        const int j    = threadIdx.x & 31;
        const int t    = b + half;

        int lo = 0, len = nelems;
        #pragma unroll
        for (int round = 0; round < 4; ++round) {
            int pos = lo + (int)(((long long)j * len) >> 5);
            int v = seg[pos];
            unsigned long long m = __ballot(v < t);
            unsigned mh = half ? (unsigned)(m >> 32) : (unsigned)(m & 0xffffffffull);
            int c = __popc(mh);
            int pcm1 = lo + (int)(((long long)(c - 1) * len) >> 5);
            int pc   = (c < 32) ? (lo + (int)(((long long)c * len) >> 5)) : (lo + len);
            int newlo = (c > 0) ? pcm1 : lo;
            int newhi = (c > 0) ? pc : lo;    // c==0 -> seg[lo] >= t -> lb == lo
            lo = newlo;
            len = newhi - newlo;
        }
        // final: len <= 32
        int v = (j < len) ? seg[lo + j] : 0x7fffffff;
        unsigned long long m = __ballot(v < t);
        unsigned mh = half ? (unsigned)(m >> 32) : (unsigned)(m & 0xffffffffull);
        if (j == 0) sb[half] = lo + __popc(mh);
    }
    __syncthreads();

    const int start = sb[0];
    const int end   = sb[1];

    f32x4 a0 = (f32x4)0.f, a1 = (f32x4)0.f, a2 = (f32x4)0.f, a3 = (f32x4)0.f;

    int r = start + rl;
    for (; r + 3 * ROWLANES < end; r += 4 * ROWLANES) {
        f32x4 v0 = __builtin_nontemporal_load(&mem[(size_t)r * F4 + lane]);
        f32x4 v1 = __builtin_nontemporal_load(&mem[(size_t)(r + ROWLANES) * F4 + lane]);
        f32x4 v2 = __builtin_nontemporal_load(&mem[(size_t)(r + 2 * ROWLANES) * F4 + lane]);
        f32x4 v3 = __builtin_nontemporal_load(&mem[(size_t)(r + 3 * ROWLANES) * F4 + lane]);
        a0 += v0; a1 += v1; a2 += v2; a3 += v3;
    }
    for (; r < end; r += ROWLANES) {
        a0 += __builtin_nontemporal_load(&mem[(size_t)r * F4 + lane]);
    }
    a0 += a1; a2 += a3; a0 += a2;

    // Reduce across the 16 row-lanes via LDS (two stages).
    __shared__ f32x4 red[ROWLANES][F4];
    red[rl][lane] = a0;
    __syncthreads();
    if (rl < 4) {
        red[rl][lane] = red[rl][lane] + red[rl + 4][lane] +
                        red[rl + 8][lane] + red[rl + 12][lane];
    }
    __syncthreads();
    if (rl == 0) {
        f32x4 s = red[0][lane] + red[1][lane] + red[2][lane] + red[3][lane];
        out[(size_t)b * F4 + lane] = s;   // covers empty segments (zeros)
    }
}

extern "C" void kernel_launch(void* const* d_in, const int* in_sizes, int n_in,
                              void* d_out, int out_size, void* d_ws, size_t ws_size,
                              hipStream_t stream) {
    const f32x4* mem = (const f32x4*)d_in[0];
    const int* seg = (const int*)d_in[1];
    f32x4* out = (f32x4*)d_out;

    const int nelems = in_sizes[1];     // 1,000,000
    const int nseg = out_size / FEAT;   // 1024

    segsum_fused<<<nseg, THREADS, 0, stream>>>(mem, seg, out, nelems);
}